// Round 12
// baseline (302.145 us; speedup 1.0000x reference)
//
#include <hip/hip_runtime.h>
#include <hip/hip_bf16.h>
#include <math.h>

// MMD (InfoVAE RBF kernel), N=8192, D=128, fp32 in, scalar fp32 out.
//
// Round 12: software-pipelined phase stream (r11's B-from-L2 REVERTED —
//   it regressed 56.5->80 us: per-wave L2 loads expose full latency;
//   DMA->LDS staging decouples it).
//   - Unified Z = [X;Y]: MMD*N^2 = sum s_i s_j k(z_i,z_j); upper-triangle
//     128x128 tiles (8256), uniform +-1/+-2 tile weights.
//   - 2 tiles/block (grid 4128), 8 K-quarter phases per block. Two 16 KB
//     LDS buffers (A-qtr 8 KB + B-qtr 8 KB each) ping-pong:
//     issue DMA(ph+1) -> compute(ph) -> barrier. Prefetch is in flight for
//     the entire compute phase, so the compiler's vmcnt(0)-before-s_barrier
//     drain is nearly free; only phase 0 is exposed (once per block).
//     1 barrier/phase (r10 had 2), epilogue runs before the tile's last
//     barrier for extra hiding. LDS 32 KB -> 4 blocks/CU.
//   - XOR-4 swizzle per 64-B row (LDS chunk c of row r holds global chunk
//     c^(r&3)): ds_read_b128 spreads 8 lanes per bank-group (optimal).
//     DMA offset arg ALWAYS 0 (r8/r9 bug: it applies LDS-side).
//   - Fused finish via completion counter (exonerated by r9/r10 forensics).
//   Numerics (r3-r10): bf16 MFMA arg noise zero-mean -> ~2e-9 MMD shift;
//   exp2 HW bias cancels in +1+1-2; fp32 per-tile partials (<=16); fp64
//   across tiles/blocks. absmax held at 5.96e-8 (threshold 7.15e-8).

#define NN 8192
#define DD 128
#define TZ 16384
#define TILES 128
#define NTILES (TILES * (TILES + 1) / 2)   // 8256
#define GRID (NTILES / 2)                  // 4128 blocks, 2 tiles each

typedef __attribute__((ext_vector_type(8))) short bf16x8;
typedef __attribute__((ext_vector_type(4))) float f32x4;
typedef __attribute__((ext_vector_type(2))) float f32x2;

#if __has_builtin(__builtin_amdgcn_exp2f)
#define EXP2F __builtin_amdgcn_exp2f
#else
#define EXP2F exp2f
#endif

constexpr float LOG2E = 0x1.715476p+0f;
constexpr float S2 = LOG2E / 8192.0f;              // 2*log2e/16384

// ---- ws layout ----
constexpr size_t WS_CTR  = 512;
constexpr size_t WS_NORM = 768;
constexpr size_t WS_Z    = WS_NORM + (size_t)TZ * sizeof(float);

__device__ __forceinline__ void gload_lds16(const void* g, void* l) {
  __builtin_amdgcn_global_load_lds(
      (const __attribute__((address_space(1))) void*)g,
      (__attribute__((address_space(3))) void*)l, 16, 0, 0);
}

__global__ __launch_bounds__(256) void prep(
    const float* __restrict__ X, const float* __restrict__ Y,
    __hip_bfloat16* __restrict__ Z, float* __restrict__ normZ,
    double* __restrict__ sums, unsigned* __restrict__ ctr) {
  if (blockIdx.x == 0) {
    if (threadIdx.x < 64) sums[threadIdx.x] = 0.0;
    if (threadIdx.x == 64) *ctr = 0u;
  }

  const int row = blockIdx.x * 4 + (threadIdx.x >> 6);
  const int lane = threadIdx.x & 63;
  const float* __restrict__ src =
      (row < NN) ? (X + (size_t)row * DD) : (Y + (size_t)(row - NN) * DD);
  const float2 v = *reinterpret_cast<const float2*>(src + 2 * lane);

  float n = v.x * v.x + v.y * v.y;
  *reinterpret_cast<__hip_bfloat162*>(Z + (size_t)row * DD + 2 * lane) =
      __hip_bfloat162{__float2bfloat16(v.x), __float2bfloat16(v.y)};

#pragma unroll
  for (int o = 32; o > 0; o >>= 1) n += __shfl_down(n, o);
  if (lane == 0) normZ[row] = n * (-LOG2E / 16384.0f);  // pre-scaled
}

__device__ __forceinline__ int tri_start(int i) {
  return i * TILES - (i * (i - 1)) / 2;
}

// Stage one 16 KB phase buffer: A-qtr rows of tile-row I, B-qtr of J,
// K-quarter kp. Wave w issues segments {w, w+4} of each panel.
// laneOff = sr*256 + ((sc ^ (sr&3))*16), sr=lane>>2, sc=lane&3.
__device__ __forceinline__ void stage_phase(
    const char* Zb, char* lds, int I, int J, int kp, int bufIdx,
    int wave, int laneOff) {
  char* buf = lds + bufIdx * 16384;
  const char* gA = Zb + (size_t)I * 32768 + kp * 64 + laneOff;
  const char* gB = Zb + (size_t)J * 32768 + kp * 64 + laneOff;
  gload_lds16(gA + wave * 4096,       buf + wave * 1024);
  gload_lds16(gA + (wave + 4) * 4096, buf + (wave + 4) * 1024);
  gload_lds16(gB + wave * 4096,       buf + 8192 + wave * 1024);
  gload_lds16(gB + (wave + 4) * 4096, buf + 8192 + (wave + 4) * 1024);
}

__global__ __launch_bounds__(256, 4) void mmd_mfma(
    const __hip_bfloat16* __restrict__ Z, const float* __restrict__ normZ,
    double* __restrict__ sums, unsigned* __restrict__ ctr,
    float* __restrict__ out) {
  __shared__ alignas(16) char lds[32768];        // 2 x 16 KB phase buffers
  __shared__ double red[4];
  __shared__ bool amLast;

  const int t0 = 2 * blockIdx.x;
  int I0 = (int)((257.0 - sqrt(257.0 * 257.0 - 8.0 * (double)t0)) * 0.5);
  if (I0 > 127) I0 = 127;
  if (I0 < 0) I0 = 0;
  while (I0 < 127 && tri_start(I0 + 1) <= t0) ++I0;
  while (I0 > 0 && tri_start(I0) > t0) --I0;
  int J0 = I0 + (t0 - tri_start(I0));
  int I1 = I0, J1 = J0 + 1;
  if (J1 >= TILES) { I1 = I0 + 1; J1 = I1; }

  const int tid = threadIdx.x;
  const int lane = tid & 63, wave = tid >> 6;
  const int wr = wave >> 1, wc = wave & 1;       // 2x2 wave grid over 128x128
  const int lr = lane & 15, quad = lane >> 4;    // MFMA lane decomposition

  // Staging lane geometry (see stage_phase).
  const int sr = lane >> 2, sc = lane & 3;
  const int laneOff = sr * 256 + ((sc ^ (sr & 3)) * 16);

  // Fragment read offsets within a phase buffer (row stride 64 B, XOR-4):
  const int aOff = (wr * 64 + lr) * 64 + ((quad ^ (lr & 3)) * 16);
  const int bOff = 8192 + (wc * 64 + lr) * 64 + ((quad ^ (lr & 3)) * 16);

  const char* Zb = (const char*)Z;
  const f32x2 s2v = {S2, S2};
  double local = 0.0;

  stage_phase(Zb, lds, I0, J0, 0, 0, wave, laneOff);
  __syncthreads();  // drain phase 0 (only exposed DMA)

#pragma unroll
  for (int t = 0; t < 2; ++t) {
    const int I = t ? I1 : I0;
    const int J = t ? J1 : J0;

    // Per-tile norm registers.
    f32x2 ar01[4], ar23[4];
    float cn[4];
#pragma unroll
    for (int i = 0; i < 4; ++i) {
      const float* p = normZ + I * 128 + wr * 64 + i * 16 + quad * 4;
      const float2 v01 = *reinterpret_cast<const float2*>(p);
      const float2 v23 = *reinterpret_cast<const float2*>(p + 2);
      ar01[i] = (f32x2){v01.x, v01.y};
      ar23[i] = (f32x2){v23.x, v23.y};
    }
#pragma unroll
    for (int j = 0; j < 4; ++j)
      cn[j] = normZ[J * 128 + wc * 64 + j * 16 + lr];

    f32x4 acc[4][4] = {};
#pragma unroll
    for (int kp = 0; kp < 4; ++kp) {
      const int ph = t * 4 + kp;
      if (ph < 7) {                      // prefetch next phase, other buffer
        const int np = ph + 1;
        stage_phase(Zb, lds, (np < 4) ? I0 : I1, (np < 4) ? J0 : J1,
                    np & 3, np & 1, wave, laneOff);
      }
      const char* buf = lds + (ph & 1) * 16384;
      bf16x8 a[4], bf[4];
#pragma unroll
      for (int i = 0; i < 4; ++i)
        a[i] = *reinterpret_cast<const bf16x8*>(buf + aOff + i * 1024);
#pragma unroll
      for (int j = 0; j < 4; ++j)
        bf[j] = *reinterpret_cast<const bf16x8*>(buf + bOff + j * 1024);
#pragma unroll
      for (int i = 0; i < 4; ++i)
#pragma unroll
        for (int j = 0; j < 4; ++j)
          acc[i][j] = __builtin_amdgcn_mfma_f32_16x16x32_bf16(
              a[i], bf[j], acc[i][j], 0, 0, 0);

      if (kp == 3) {
        // Tile epilogue before the barrier (extra DMA-hiding time).
        f32x2 part01 = {0.f, 0.f}, part23 = {0.f, 0.f};
#pragma unroll
        for (int i = 0; i < 4; ++i) {
#pragma unroll
          for (int j = 0; j < 4; ++j) {
            const f32x2 rb2 = {cn[j], cn[j]};
            const f32x2 base01 = ar01[i] + rb2;
            const f32x2 base23 = ar23[i] + rb2;
            const f32x2 acc01 = {acc[i][j][0], acc[i][j][1]};
            const f32x2 acc23 = {acc[i][j][2], acc[i][j][3]};
            const f32x2 arg01 = __builtin_elementwise_fma(acc01, s2v, base01);
            const f32x2 arg23 = __builtin_elementwise_fma(acc23, s2v, base23);
            part01 += (f32x2){EXP2F(arg01.x), EXP2F(arg01.y)};
            part23 += (f32x2){EXP2F(arg23.x), EXP2F(arg23.y)};
          }
        }
        const f32x2 ps = part01 + part23;
        double w = ((I < 64) == (J < 64)) ? 1.0 : -1.0;
        if (I != J) w += w;
        local += w * (double)(ps.x + ps.y);
      }
      __syncthreads();  // drains DMA(ph+1); orders buffer reuse
    }
  }

  // Block reduction + one global atomic + fused finish.
#pragma unroll
  for (int o = 32; o > 0; o >>= 1) local += __shfl_down(local, o);
  if (lane == 0) red[wave] = local;
  __syncthreads();
  if (tid == 0) {
    atomicAdd(&sums[blockIdx.x & 63], red[0] + red[1] + red[2] + red[3]);
    __threadfence();
    const unsigned prev = atomicAdd(ctr, 1u);
    amLast = (prev == GRID - 1);
  }
  __syncthreads();
  if (amLast && wave == 0) {
    double v = atomicAdd(&sums[lane], 0.0);  // device-scope coherent read
#pragma unroll
    for (int o = 32; o > 0; o >>= 1) v += __shfl_down(v, o);
    if (lane == 0)
      out[0] = (float)(v * (1.0 / ((double)NN * (double)NN)));
  }
}

extern "C" void kernel_launch(void* const* d_in, const int* in_sizes, int n_in,
                              void* d_out, int out_size, void* d_ws, size_t ws_size,
                              hipStream_t stream) {
  const float* y_inputs = (const float*)d_in[0];  // "inputs"
  const float* x_true   = (const float*)d_in[1];  // "true_samples"
  float* out = (float*)d_out;

  char* ws = (char*)d_ws;
  double* sums = (double*)ws;                     // 64 fp64 partial slots
  unsigned* ctr = (unsigned*)(ws + WS_CTR);
  float* normZ = (float*)(ws + WS_NORM);
  __hip_bfloat16* Z = (__hip_bfloat16*)(ws + WS_Z);

  prep<<<TZ / 4, 256, 0, stream>>>(x_true, y_inputs, Z, normZ, sums, ctr);
  mmd_mfma<<<GRID, 256, 0, stream>>>(Z, normZ, sums, ctr, out);
}

// Round 13
// 223.748 us; speedup vs baseline: 1.3504x; 1.3504x over previous
//
#include <hip/hip_runtime.h>
#include <hip/hip_bf16.h>
#include <math.h>

// MMD (InfoVAE RBF kernel), N=8192, D=128, fp32 in, scalar fp32 out.
//
// Round 13: r10 (proven 56.5 us main, VGPR 56, 0 conflicts) + fused finish
//   + one fewer barrier. r11 (B-from-L2) and r12 (persistent phase pipeline)
//   both REGRESSED: r11 exposed raw L2 latency per-wave (MfmaUtil 25->17);
//   r12 spilled to scratch (WRITE_SIZE 186 MB, MfmaUtil 5.5) from two-tile
//   bookkeeping under the (256,4) reg cap + 4-way conflicts from 64-B rows.
//   Lesson (matches guide m99-m141): don't over-engineer pipelining on the
//   2-barrier K-loop; keep the register-lean single-tile structure.
//   - Unified Z = [X;Y]: MMD*N^2 = sum s_i s_j k(z_i,z_j); upper-triangle
//     128x128 tiles (8256), uniform +-1/+-2 tile weights.
//   - Staging via global_load_lds(16B), offset arg ALWAYS 0 (r8/r9: the
//     builtin's imm offset applies LDS-side -> corrupts). XOR-8 swizzle
//     (LDS chunk c of row r holds global chunk c^(r&7), 128-B rows):
//     ds_read_b128 spreads 8 lanes per bank-group -> conflict-free.
//     LDS ~35 KB -> 4 blocks/CU at launch_bounds(256,4); VGPR 56+64 acc.
//   - Fused finish: per-block fp64 atomic -> threadfence -> completion ctr;
//     last block re-reads the 64 slots via atomicAdd(+0.0). Exonerated by
//     r8-vs-r9 bit-identical-absmax forensics.
//   Numerics (r3-r10): bf16 MFMA arg noise zero-mean -> ~2e-9 MMD shift;
//   exp2 HW bias cancels in +1+1-2; fp32 per-tile partials (<=16); fp64
//   across blocks. absmax held at 5.96e-8 (threshold 7.15e-8).

#define NN 8192
#define DD 128
#define TZ 16384
#define TILES 128
#define NBLOCKS (TILES * (TILES + 1) / 2)   // 8256

typedef __attribute__((ext_vector_type(8))) short bf16x8;
typedef __attribute__((ext_vector_type(4))) float f32x4;
typedef __attribute__((ext_vector_type(2))) float f32x2;

#if __has_builtin(__builtin_amdgcn_exp2f)
#define EXP2F __builtin_amdgcn_exp2f
#else
#define EXP2F exp2f
#endif

constexpr float LOG2E = 0x1.715476p+0f;
constexpr float S2 = LOG2E / 8192.0f;              // 2*log2e/16384

constexpr int PANEL = 16384;                       // 128 rows x 128 B (one K=64 phase)

// ---- ws layout ----
constexpr size_t WS_CTR  = 512;
constexpr size_t WS_NORM = 768;
constexpr size_t WS_Z    = WS_NORM + (size_t)TZ * sizeof(float);

__device__ __forceinline__ void gload_lds16(const void* g, void* l) {
  __builtin_amdgcn_global_load_lds(
      (const __attribute__((address_space(1))) void*)g,
      (__attribute__((address_space(3))) void*)l, 16, 0, 0);
}

__global__ __launch_bounds__(256) void prep(
    const float* __restrict__ X, const float* __restrict__ Y,
    __hip_bfloat16* __restrict__ Z, float* __restrict__ normZ,
    double* __restrict__ sums, unsigned* __restrict__ ctr) {
  if (blockIdx.x == 0) {
    if (threadIdx.x < 64) sums[threadIdx.x] = 0.0;
    if (threadIdx.x == 64) *ctr = 0u;
  }

  const int row = blockIdx.x * 4 + (threadIdx.x >> 6);
  const int lane = threadIdx.x & 63;
  const float* __restrict__ src =
      (row < NN) ? (X + (size_t)row * DD) : (Y + (size_t)(row - NN) * DD);
  const float2 v = *reinterpret_cast<const float2*>(src + 2 * lane);

  float n = v.x * v.x + v.y * v.y;
  *reinterpret_cast<__hip_bfloat162*>(Z + (size_t)row * DD + 2 * lane) =
      __hip_bfloat162{__float2bfloat16(v.x), __float2bfloat16(v.y)};

#pragma unroll
  for (int o = 32; o > 0; o >>= 1) n += __shfl_down(n, o);
  if (lane == 0) normZ[row] = n * (-LOG2E / 16384.0f);  // pre-scaled
}

__device__ __forceinline__ int tri_start(int i) {
  return i * TILES - (i * (i - 1)) / 2;
}

__global__ __launch_bounds__(256, 4) void mmd_mfma(
    const __hip_bfloat16* __restrict__ Z, const float* __restrict__ normZ,
    double* __restrict__ sums, unsigned* __restrict__ ctr,
    float* __restrict__ out) {
  __shared__ alignas(16) char lds[2 * PANEL + 1024];  // +1 KB sacrificial pad
  __shared__ float rowN[128], colN[128];
  __shared__ double red[4];
  __shared__ bool amLast;

  const int t = blockIdx.x;
  int I = (int)((257.0 - sqrt(257.0 * 257.0 - 8.0 * (double)t)) * 0.5);
  if (I > 127) I = 127;
  if (I < 0) I = 0;
  while (I < 127 && tri_start(I + 1) <= t) ++I;
  while (I > 0 && tri_start(I) > t) --I;
  const int J = I + (t - tri_start(I));

  const int tid = threadIdx.x;
  const int lane = tid & 63, wave = tid >> 6;
  const int wr = wave >> 1, wc = wave & 1;       // 2x2 wave grid over 128x128
  const int lr = lane & 15, quad = lane >> 4;    // MFMA lane decomposition

  if (tid < 128) rowN[tid] = normZ[I * 128 + tid];
  else           colN[tid - 128] = normZ[J * 128 + tid - 128];

  // Staging: lane of wave w, issue l covers row = 8w + (lane>>3) + 32l,
  // LDS chunk c = lane&7 holds global chunk g = c ^ (row&7) (l-invariant).
  // Each global row is 256 B; phase p selects the 128-B half via +p*128
  // folded into the global pointer (NO builtin offset arg).
  const char* Zb = (const char*)Z;
  const int r5 = tid >> 3;                       // 0..31
  const int g = (tid & 7) ^ (r5 & 7);
  const char* gA = Zb + (size_t)I * 32768 + r5 * 256 + g * 16;
  const char* gB = Zb + (size_t)J * 32768 + r5 * 256 + g * 16;
  char* lw = lds + wave * 1024;                  // wave-uniform LDS base

  // MFMA LDS read bases (swizzled chunk: (ks*4+quad) ^ (lr&7), bits disjoint).
  const int aBase = (wr * 64 + lr) * 128;
  const int bBase = PANEL + (wc * 64 + lr) * 128;
  const int sa = lr & 7;

  f32x4 acc[4][4] = {};
#pragma unroll
  for (int p = 0; p < 2; ++p) {
    // p==0: no reuse to guard -> skip the leading barrier (the drain
    // barrier below also publishes rowN/colN before any epilogue read).
    if (p == 1) __syncthreads();  // all waves done reading phase-0 data
#pragma unroll
    for (int l = 0; l < 4; ++l) {
      gload_lds16(gA + p * 128 + l * 8192, lw + l * 4096);
      gload_lds16(gB + p * 128 + l * 8192, lw + PANEL + l * 4096);
    }
    __syncthreads();  // drains vmcnt (global_load_lds completion)

#pragma unroll
    for (int ks = 0; ks < 2; ++ks) {
      const int csw = (((ks * 4) + quad) ^ sa) * 16;
      bf16x8 a[4], b[4];
#pragma unroll
      for (int i = 0; i < 4; ++i) {
        a[i] = *reinterpret_cast<const bf16x8*>(&lds[aBase + i * 2048 + csw]);
        b[i] = *reinterpret_cast<const bf16x8*>(&lds[bBase + i * 2048 + csw]);
      }
#pragma unroll
      for (int i = 0; i < 4; ++i)
#pragma unroll
        for (int j = 0; j < 4; ++j)
          acc[i][j] = __builtin_amdgcn_mfma_f32_16x16x32_bf16(a[i], b[j], acc[i][j], 0, 0, 0);
    }
  }

  // Epilogue (C/D: col=lane&15, row=quad*4+reg), packed fp32 pairs:
  // k = exp2(acc*S2 + ra + rb), ra/rb pre-scaled by -log2e/16384.
  const f32x2 s2v = {S2, S2};
  f32x2 part01 = {0.f, 0.f}, part23 = {0.f, 0.f};
#pragma unroll
  for (int i = 0; i < 4; ++i) {
    const int rbase = wr * 64 + i * 16 + quad * 4;
    const f32x2 ar01 = {rowN[rbase + 0], rowN[rbase + 1]};
    const f32x2 ar23 = {rowN[rbase + 2], rowN[rbase + 3]};
#pragma unroll
    for (int j = 0; j < 4; ++j) {
      const float rb = colN[wc * 64 + j * 16 + lr];
      const f32x2 rb2 = {rb, rb};
      const f32x2 base01 = ar01 + rb2;
      const f32x2 base23 = ar23 + rb2;
      const f32x2 acc01 = {acc[i][j][0], acc[i][j][1]};
      const f32x2 acc23 = {acc[i][j][2], acc[i][j][3]};
      const f32x2 arg01 = __builtin_elementwise_fma(acc01, s2v, base01);
      const f32x2 arg23 = __builtin_elementwise_fma(acc23, s2v, base23);
      part01 += (f32x2){EXP2F(arg01.x), EXP2F(arg01.y)};
      part23 += (f32x2){EXP2F(arg23.x), EXP2F(arg23.y)};
    }
  }
  const f32x2 ps = part01 + part23;
  double local = (double)(ps.x + ps.y);
  double w = ((I < 64) == (J < 64)) ? 1.0 : -1.0;
  if (I != J) w += w;
  local *= w;

  // Block reduction + one global atomic + fused finish.
#pragma unroll
  for (int o = 32; o > 0; o >>= 1) local += __shfl_down(local, o);
  if (lane == 0) red[wave] = local;
  __syncthreads();
  if (tid == 0) {
    atomicAdd(&sums[t & 63], red[0] + red[1] + red[2] + red[3]);
    __threadfence();  // publish before signaling completion
    const unsigned prev = atomicAdd(ctr, 1u);
    amLast = (prev == NBLOCKS - 1);
  }
  __syncthreads();
  if (amLast && wave == 0) {
    double v = atomicAdd(&sums[lane], 0.0);  // device-scope coherent read
#pragma unroll
    for (int o = 32; o > 0; o >>= 1) v += __shfl_down(v, o);
    if (lane == 0)
      out[0] = (float)(v * (1.0 / ((double)NN * (double)NN)));
  }
}

extern "C" void kernel_launch(void* const* d_in, const int* in_sizes, int n_in,
                              void* d_out, int out_size, void* d_ws, size_t ws_size,
                              hipStream_t stream) {
  const float* y_inputs = (const float*)d_in[0];  // "inputs"
  const float* x_true   = (const float*)d_in[1];  // "true_samples"
  float* out = (float*)d_out;

  char* ws = (char*)d_ws;
  double* sums = (double*)ws;                     // 64 fp64 partial slots
  unsigned* ctr = (unsigned*)(ws + WS_CTR);
  float* normZ = (float*)(ws + WS_NORM);
  __hip_bfloat16* Z = (__hip_bfloat16*)(ws + WS_Z);

  prep<<<TZ / 4, 256, 0, stream>>>(x_true, y_inputs, Z, normZ, sums, ctr);
  mmd_mfma<<<NBLOCKS, 256, 0, stream>>>(Z, normZ, sums, ctr, out);
}

// Round 14
// 112.968 us; speedup vs baseline: 2.6746x; 1.9806x over previous
//
#include <hip/hip_runtime.h>
#include <hip/hip_bf16.h>
#include <math.h>

// MMD (InfoVAE RBF kernel), N=8192, D=128, fp32 in, scalar fp32 out.
//
// Round 14: exact r10 structure (the 110.3 us / main 56.5 us config) with
//   ONLY the p==0 barrier drop kept. r13's fused finish REVERTED:
//   per-block __threadfence() (device-scope -> L2 writeback/invalidate on
//   gfx950) x 8256 blocks thrashed the L2-resident Z for concurrent blocks
//   -> staging fell to L3 (FETCH_SIZE unchanged, both pipes idle, wall
//   3.4x). Single-address ctr RMW added tail serialization. Separate
//   finish kernel is the proven-safe cross-block reduction.
//   - Unified Z = [X;Y]: MMD*N^2 = sum s_i s_j k(z_i,z_j); upper-triangle
//     128x128 tiles (8256), uniform +-1/+-2 tile weights.
//   - Staging via global_load_lds(16B), offset arg ALWAYS 0 (r8/r9: the
//     builtin's imm offset applies LDS-side -> corrupts). XOR-8 swizzle
//     (LDS chunk c of row r holds global chunk c^(r&7), 128-B rows):
//     ds_read_b128 spreads 8 lanes per bank-group -> conflict-free.
//     LDS ~35 KB -> 4 blocks/CU at launch_bounds(256,4); VGPR 56 + 64 acc.
//   - DO NOT: fuse finish w/ threadfence (r13), stage B per-wave from L2
//     (r11), multi-tile persistent pipelining under the reg cap (r12).
//   Numerics (r3-r10): bf16 MFMA arg noise zero-mean -> ~2e-9 MMD shift;
//   exp2 HW bias cancels in +1+1-2; fp32 per-tile partials (<=16); fp64
//   across blocks. absmax held at 5.96e-8 (threshold 7.15e-8).

#define NN 8192
#define DD 128
#define TZ 16384
#define TILES 128
#define NBLOCKS (TILES * (TILES + 1) / 2)   // 8256

typedef __attribute__((ext_vector_type(8))) short bf16x8;
typedef __attribute__((ext_vector_type(4))) float f32x4;
typedef __attribute__((ext_vector_type(2))) float f32x2;

#if __has_builtin(__builtin_amdgcn_exp2f)
#define EXP2F __builtin_amdgcn_exp2f
#else
#define EXP2F exp2f
#endif

constexpr float LOG2E = 0x1.715476p+0f;
constexpr float S2 = LOG2E / 8192.0f;              // 2*log2e/16384

constexpr int PANEL = 16384;                       // 128 rows x 128 B (one K=64 phase)

// ---- ws layout ----
constexpr size_t WS_NORM = 768;
constexpr size_t WS_Z    = WS_NORM + (size_t)TZ * sizeof(float);

__device__ __forceinline__ void gload_lds16(const void* g, void* l) {
  __builtin_amdgcn_global_load_lds(
      (const __attribute__((address_space(1))) void*)g,
      (__attribute__((address_space(3))) void*)l, 16, 0, 0);
}

__global__ __launch_bounds__(256) void prep(
    const float* __restrict__ X, const float* __restrict__ Y,
    __hip_bfloat16* __restrict__ Z, float* __restrict__ normZ,
    double* __restrict__ sums) {
  if (blockIdx.x == 0 && threadIdx.x < 64) sums[threadIdx.x] = 0.0;

  const int row = blockIdx.x * 4 + (threadIdx.x >> 6);
  const int lane = threadIdx.x & 63;
  const float* __restrict__ src =
      (row < NN) ? (X + (size_t)row * DD) : (Y + (size_t)(row - NN) * DD);
  const float2 v = *reinterpret_cast<const float2*>(src + 2 * lane);

  float n = v.x * v.x + v.y * v.y;
  *reinterpret_cast<__hip_bfloat162*>(Z + (size_t)row * DD + 2 * lane) =
      __hip_bfloat162{__float2bfloat16(v.x), __float2bfloat16(v.y)};

#pragma unroll
  for (int o = 32; o > 0; o >>= 1) n += __shfl_down(n, o);
  if (lane == 0) normZ[row] = n * (-LOG2E / 16384.0f);  // pre-scaled
}

__device__ __forceinline__ int tri_start(int i) {
  return i * TILES - (i * (i - 1)) / 2;
}

__global__ __launch_bounds__(256, 4) void mmd_mfma(
    const __hip_bfloat16* __restrict__ Z, const float* __restrict__ normZ,
    double* __restrict__ sums) {
  __shared__ alignas(16) char lds[2 * PANEL + 1024];  // +1 KB sacrificial pad
  __shared__ float rowN[128], colN[128];
  __shared__ double red[4];

  const int t = blockIdx.x;
  int I = (int)((257.0 - sqrt(257.0 * 257.0 - 8.0 * (double)t)) * 0.5);
  if (I > 127) I = 127;
  if (I < 0) I = 0;
  while (I < 127 && tri_start(I + 1) <= t) ++I;
  while (I > 0 && tri_start(I) > t) --I;
  const int J = I + (t - tri_start(I));

  const int tid = threadIdx.x;
  const int lane = tid & 63, wave = tid >> 6;
  const int wr = wave >> 1, wc = wave & 1;       // 2x2 wave grid over 128x128
  const int lr = lane & 15, quad = lane >> 4;    // MFMA lane decomposition

  if (tid < 128) rowN[tid] = normZ[I * 128 + tid];
  else           colN[tid - 128] = normZ[J * 128 + tid - 128];

  // Staging: lane of wave w, issue l covers row = 8w + (lane>>3) + 32l,
  // LDS chunk c = lane&7 holds global chunk g = c ^ (row&7) (l-invariant).
  // Each global row is 256 B; phase p selects the 128-B half via +p*128
  // folded into the global pointer (NO builtin offset arg).
  const char* Zb = (const char*)Z;
  const int r5 = tid >> 3;                       // 0..31
  const int g = (tid & 7) ^ (r5 & 7);
  const char* gA = Zb + (size_t)I * 32768 + r5 * 256 + g * 16;
  const char* gB = Zb + (size_t)J * 32768 + r5 * 256 + g * 16;
  char* lw = lds + wave * 1024;                  // wave-uniform LDS base

  // MFMA LDS read bases (swizzled chunk: (ks*4+quad) ^ (lr&7), bits disjoint).
  const int aBase = (wr * 64 + lr) * 128;
  const int bBase = PANEL + (wc * 64 + lr) * 128;
  const int sa = lr & 7;

  f32x4 acc[4][4] = {};
#pragma unroll
  for (int p = 0; p < 2; ++p) {
    // p==0: nothing to guard before the first DMA issue (rowN/colN live in
    // separate LDS arrays); the drain barrier below publishes them too.
    if (p == 1) __syncthreads();  // all waves done reading phase-0 data
#pragma unroll
    for (int l = 0; l < 4; ++l) {
      gload_lds16(gA + p * 128 + l * 8192, lw + l * 4096);
      gload_lds16(gB + p * 128 + l * 8192, lw + PANEL + l * 4096);
    }
    __syncthreads();  // drains vmcnt (global_load_lds completion)

#pragma unroll
    for (int ks = 0; ks < 2; ++ks) {
      const int csw = (((ks * 4) + quad) ^ sa) * 16;
      bf16x8 a[4], b[4];
#pragma unroll
      for (int i = 0; i < 4; ++i) {
        a[i] = *reinterpret_cast<const bf16x8*>(&lds[aBase + i * 2048 + csw]);
        b[i] = *reinterpret_cast<const bf16x8*>(&lds[bBase + i * 2048 + csw]);
      }
#pragma unroll
      for (int i = 0; i < 4; ++i)
#pragma unroll
        for (int j = 0; j < 4; ++j)
          acc[i][j] = __builtin_amdgcn_mfma_f32_16x16x32_bf16(a[i], b[j], acc[i][j], 0, 0, 0);
    }
  }

  // Epilogue (C/D: col=lane&15, row=quad*4+reg), packed fp32 pairs:
  // k = exp2(acc*S2 + ra + rb), ra/rb pre-scaled by -log2e/16384.
  const f32x2 s2v = {S2, S2};
  f32x2 part01 = {0.f, 0.f}, part23 = {0.f, 0.f};
#pragma unroll
  for (int i = 0; i < 4; ++i) {
    const int rbase = wr * 64 + i * 16 + quad * 4;
    const f32x2 ar01 = {rowN[rbase + 0], rowN[rbase + 1]};
    const f32x2 ar23 = {rowN[rbase + 2], rowN[rbase + 3]};
#pragma unroll
    for (int j = 0; j < 4; ++j) {
      const float rb = colN[wc * 64 + j * 16 + lr];
      const f32x2 rb2 = {rb, rb};
      const f32x2 base01 = ar01 + rb2;
      const f32x2 base23 = ar23 + rb2;
      const f32x2 acc01 = {acc[i][j][0], acc[i][j][1]};
      const f32x2 acc23 = {acc[i][j][2], acc[i][j][3]};
      const f32x2 arg01 = __builtin_elementwise_fma(acc01, s2v, base01);
      const f32x2 arg23 = __builtin_elementwise_fma(acc23, s2v, base23);
      part01 += (f32x2){EXP2F(arg01.x), EXP2F(arg01.y)};
      part23 += (f32x2){EXP2F(arg23.x), EXP2F(arg23.y)};
    }
  }
  const f32x2 ps = part01 + part23;
  double local = (double)(ps.x + ps.y);
  double w = ((I < 64) == (J < 64)) ? 1.0 : -1.0;
  if (I != J) w += w;
  local *= w;

#pragma unroll
  for (int o = 32; o > 0; o >>= 1) local += __shfl_down(local, o);
  if (lane == 0) red[wave] = local;
  __syncthreads();
  if (tid == 0) atomicAdd(&sums[t & 63], red[0] + red[1] + red[2] + red[3]);
}

__global__ void finish(const double* __restrict__ s, float* __restrict__ out) {
  double v = s[threadIdx.x];
#pragma unroll
  for (int o = 32; o > 0; o >>= 1) v += __shfl_down(v, o);
  if (threadIdx.x == 0)
    out[0] = (float)(v * (1.0 / ((double)NN * (double)NN)));
}

extern "C" void kernel_launch(void* const* d_in, const int* in_sizes, int n_in,
                              void* d_out, int out_size, void* d_ws, size_t ws_size,
                              hipStream_t stream) {
  const float* y_inputs = (const float*)d_in[0];  // "inputs"
  const float* x_true   = (const float*)d_in[1];  // "true_samples"
  float* out = (float*)d_out;

  char* ws = (char*)d_ws;
  double* sums = (double*)ws;                     // 64 fp64 partial slots
  float* normZ = (float*)(ws + WS_NORM);
  __hip_bfloat16* Z = (__hip_bfloat16*)(ws + WS_Z);

  prep<<<TZ / 4, 256, 0, stream>>>(x_true, y_inputs, Z, normZ, sums);
  mmd_mfma<<<NBLOCKS, 256, 0, stream>>>(Z, normZ, sums);
  finish<<<1, 64, 0, stream>>>(sums, out);
}